// Round 9
// baseline (182.651 us; speedup 1.0000x reference)
//
#include <hip/hip_runtime.h>
#include <cstdint>

#define NBATCH 16
#define CCH    384
#define HW     64
#define PLANE  (HW*HW)
#define NTOT   (NBATCH*PLANE)   // 65536 GEMM columns

typedef __attribute__((ext_vector_type(8))) short short8v;
typedef __attribute__((ext_vector_type(4))) float f32x4;

static __device__ __forceinline__ unsigned short f2bf(float f) {
    unsigned int x = __float_as_uint(f);
    unsigned int r = (x + 0x7fffu + ((x >> 16) & 1u)) >> 16;   // RTN-even
    return (unsigned short)r;
}
// packed f32x2 -> bf16x2 (low16 = a, high16 = b), RTE in HW
static __device__ __forceinline__ unsigned int cvtpk(float a, float b) {
    unsigned int r;
    asm("v_cvt_pk_bf16_f32 %0, %1, %2" : "=v"(r) : "v"(a), "v"(b));
    return r;
}

// ---------------- fused depthwise kernel v6b: 4 planes/block, pipelined ----------------
// block = (channel c, q4); planes n = q4 + 4*pl, pl=0..3; 256 thr = 4 waves.
// thread -> (h = wid*16 + l15, col segs {8*l16..+7} u {32+8*l16..+7})
//   == exactly the H-GEMM A-fragment this lane feeds -> P row stays in registers.
// LDS arrays all [64 rows][128 B] bf16, scheme-C rotation (v5-verified):
//   off(row,kbyte) = (kbyte + 16*(2*(row>>4)+(row&7))) & 127  -- closed, bijective
static __device__ __forceinline__ int rotC(int row) {
    return 2 * (row >> 4) + (row & 7);
}

// 8-wide 5x5 window: out[q] = bias + sum_{i,j} x[h+i-2][w0+q+j-2]*w[i][j]
static __device__ __forceinline__ void conv5x5_8(const float* __restrict__ xp, int h, int w0,
                                                 const float* __restrict__ sw0, float bias,
                                                 float out[8]) {
    #pragma unroll
    for (int q = 0; q < 8; ++q) out[q] = bias;
    #pragma unroll
    for (int i = 0; i < 5; ++i) {
        const int rt = h + i - 2;
        float f[16];
        #pragma unroll
        for (int q = 0; q < 4; ++q) {
            const int c0 = w0 - 4 + 4 * q;
            float4 v = make_float4(0.f, 0.f, 0.f, 0.f);
            if ((unsigned)rt < 64u && (unsigned)c0 <= 60u)
                v = *reinterpret_cast<const float4*>(xp + rt * HW + c0);
            f[4*q+0] = v.x; f[4*q+1] = v.y; f[4*q+2] = v.z; f[4*q+3] = v.w;
        }
        #pragma unroll
        for (int j = 0; j < 5; ++j) {
            const float wg = sw0[i * 5 + j];
            #pragma unroll
            for (int q = 0; q < 8; ++q) out[q] += f[q + j + 2] * wg;
        }
    }
}

// pack 16 fp32 -> bf16; fill H A-frags (regs); write transposed to ipT buffer
static __device__ __forceinline__ void pack_plane(const float sa[8], const float sbx[8],
                                                  char* __restrict__ tbuf,
                                                  int h, int w0a, int w0b,
                                                  short8v aH[2]) {
    unsigned int wlo[4], whi[4];
    #pragma unroll
    for (int j = 0; j < 4; ++j) {
        wlo[j] = cvtpk(sa[2*j], sa[2*j+1]);
        whi[j] = cvtpk(sbx[2*j], sbx[2*j+1]);
    }
    uint4 ua = make_uint4(wlo[0], wlo[1], wlo[2], wlo[3]);
    uint4 ub = make_uint4(whi[0], whi[1], whi[2], whi[3]);
    aH[0] = *reinterpret_cast<short8v*>(&ua);
    aH[1] = *reinterpret_cast<short8v*>(&ub);
    #pragma unroll
    for (int k = 0; k < 8; ++k) {
        const int wA   = w0a + k;
        const int offA = (2 * h + 16 * rotC(wA)) & 127;
        *reinterpret_cast<unsigned short*>(tbuf + wA * 128 + offA) =
            (unsigned short)(wlo[k >> 1] >> (16 * (k & 1)));
        const int wB   = w0b + k;
        const int offB = (2 * h + 16 * rotC(wB)) & 127;
        *reinterpret_cast<unsigned short*>(tbuf + wB * 128 + offB) =
            (unsigned short)(whi[k >> 1] >> (16 * (k & 1)));
    }
}

// spatial(plane) = BV@P + P@BH^T + bias -> bf16 store (v5-verified phase-B)
static __device__ __forceinline__ void mfma_plane(const char* __restrict__ tbuf,
                                                  const char* __restrict__ BHm,
                                                  const short8v aV[2], const short8v aH[2],
                                                  unsigned short* __restrict__ op,
                                                  int wid, int l15, int l16, float bv1) {
    #pragma unroll
    for (int nt = 0; nt < 4; ++nt) {
        const int brow = nt * 16 + l15;
        const int rotB = 16 * (2 * nt + (l15 & 7));
        f32x4 acc = (f32x4){0.f, 0.f, 0.f, 0.f};
        #pragma unroll
        for (int kk = 0; kk < 2; ++kk) {
            const int off = (kk * 64 + l16 * 16 + rotB) & 127;
            const short8v bV = *reinterpret_cast<const short8v*>(tbuf + brow * 128 + off);
            const short8v bH = *reinterpret_cast<const short8v*>(BHm  + brow * 128 + off);
            acc = __builtin_amdgcn_mfma_f32_16x16x32_bf16(aV[kk], bV, acc, 0, 0, 0);
            acc = __builtin_amdgcn_mfma_f32_16x16x32_bf16(aH[kk], bH, acc, 0, 0, 0);
        }
        #pragma unroll
        for (int r = 0; r < 4; ++r) {
            const int hh = wid * 16 + 4 * l16 + r;
            const int ww = nt * 16 + l15;
            op[hh * HW + ww] = f2bf(acc[r] + bv1);
        }
    }
}

__global__ __launch_bounds__(256)
void dw_fused(const float* __restrict__ x,
              const float* __restrict__ w0, const float* __restrict__ b0,
              const float* __restrict__ w1, const float* __restrict__ b1,
              const float* __restrict__ w2, const float* __restrict__ b2,
              const float* __restrict__ w3, const float* __restrict__ b3,
              const float* __restrict__ w4, const float* __restrict__ b4,
              const float* __restrict__ w5, const float* __restrict__ b5,
              const float* __restrict__ w6, const float* __restrict__ b6,
              unsigned short* __restrict__ spB)
{
    __shared__ char BVm[64 * 128];
    __shared__ char BHm[64 * 128];
    __shared__ char ipT0[64 * 128];
    __shared__ char ipT1[64 * 128];
    __shared__ float sw0[25];
    __shared__ float swh[21];
    __shared__ float swv[21];
    __shared__ float sb[2];

    const int tid = threadIdx.x;
    const int c   = blockIdx.x >> 2;
    const int q4  = blockIdx.x & 3;          // planes n = q4 + 4*pl

    // ---- per-channel weights (combined centered 1-D kernels) ----
    if (tid < 25) {
        sw0[tid] = w0[c * 25 + tid];
    } else if (tid < 46) {                    // horizontal: w5(21)+w3(11)+w1(7)
        const int d = tid - 25, dj = d - 10;
        float v = w5[c * 21 + d];
        if (dj >= -5 && dj <= 5) v += w3[c * 11 + dj + 5];
        if (dj >= -3 && dj <= 3) v += w1[c * 7  + dj + 3];
        swh[d] = v;
    } else if (tid < 67) {                    // vertical: w6(21)+w4(11)+w2(7)
        const int d = tid - 46, di = d - 10;
        float v = w6[c * 21 + d];
        if (di >= -5 && di <= 5) v += w4[c * 11 + di + 5];
        if (di >= -3 && di <= 3) v += w2[c * 7  + di + 3];
        swv[d] = v;
    } else if (tid == 67) {
        sb[0] = b0[c];
    } else if (tid == 68) {
        sb[1] = b1[c] + b2[c] + b3[c] + b4[c] + b5[c] + b6[c];
    }
    __syncthreads();   // B1

    // ---- band matrices (v5-verified pattern) ----
    {
        const int h2  = tid >> 2;
        const int p2  = tid & 3;
        const int ws2 = p2 << 4;
        unsigned short uv[16], uh[16];
        #pragma unroll
        for (int m = 0; m < 16; ++m) {
            const int d = ws2 + m - h2 + 10;
            const bool ok = (unsigned)d < 21u;
            uv[m] = ok ? f2bf(swv[d]) : (unsigned short)0;
            uh[m] = ok ? f2bf(swh[d]) : (unsigned short)0;
        }
        const int rot = rotC(h2);
        #pragma unroll
        for (int q = 0; q < 2; ++q) {
            const int off = ((ws2 << 1) + 16 * q + 16 * rot) & 127;
            *reinterpret_cast<uint4*>(BVm + h2 * 128 + off) =
                reinterpret_cast<const uint4*>(uv)[q];
            *reinterpret_cast<uint4*>(BHm + h2 * 128 + off) =
                reinterpret_cast<const uint4*>(uh)[q];
        }
    }

    const int lane = tid & 63;
    const int wid  = tid >> 6;
    const int l15  = lane & 15;
    const int l16  = lane >> 4;
    const int h    = wid * 16 + l15;
    const int w0a  = 8 * l16;          // kk=0 k-slice cols
    const int w0b  = 32 + 8 * l16;     // kk=1 k-slice cols
    const float b0v = sb[0];

    short8v aH0[2], aH1[2], aH2[2], aH3[2];
    float sa[8], sbx[8];

    // ---- segment 0: 5x5(pl0) + pack -> ipT0 ----
    {
        const float* xp = x + ((size_t)(q4 + 0) * CCH + c) * PLANE;
        conv5x5_8(xp, h, w0a, sw0, b0v, sa);
        conv5x5_8(xp, h, w0b, sw0, b0v, sbx);
    }
    pack_plane(sa, sbx, ipT0, h, w0a, w0b, aH0);
    __syncthreads();   // B2: bands + ipT0 ready

    // hoist V A-frags (BV rows; constant across planes)
    short8v aV[2];
    {
        const int rotA = 16 * (2 * wid + (l15 & 7));   // rotC(h), h>>4 == wid
        #pragma unroll
        for (int kk = 0; kk < 2; ++kk) {
            const int off = (kk * 64 + l16 * 16 + rotA) & 127;
            aV[kk] = *reinterpret_cast<const short8v*>(BVm + h * 128 + off);
        }
    }
    const float bv1 = sb[1];
    unsigned short* const spc = spB + (size_t)c * NBATCH * PLANE;

    // ---- segment 1: 5x5(pl1) | MFMA(pl0) | pack(pl1) -> ipT1 ----
    {
        const float* xp = x + ((size_t)(q4 + 4) * CCH + c) * PLANE;
        conv5x5_8(xp, h, w0a, sw0, b0v, sa);
        conv5x5_8(xp, h, w0b, sw0, b0v, sbx);
    }
    mfma_plane(ipT0, BHm, aV, aH0, spc + (size_t)(q4 + 0) * PLANE, wid, l15, l16, bv1);
    pack_plane(sa, sbx, ipT1, h, w0a, w0b, aH1);
    __syncthreads();

    // ---- segment 2: 5x5(pl2) | MFMA(pl1) | pack(pl2) -> ipT0 ----
    {
        const float* xp = x + ((size_t)(q4 + 8) * CCH + c) * PLANE;
        conv5x5_8(xp, h, w0a, sw0, b0v, sa);
        conv5x5_8(xp, h, w0b, sw0, b0v, sbx);
    }
    mfma_plane(ipT1, BHm, aV, aH1, spc + (size_t)(q4 + 4) * PLANE, wid, l15, l16, bv1);
    pack_plane(sa, sbx, ipT0, h, w0a, w0b, aH2);
    __syncthreads();

    // ---- segment 3: 5x5(pl3) | MFMA(pl2) | pack(pl3) -> ipT1 ----
    {
        const float* xp = x + ((size_t)(q4 + 12) * CCH + c) * PLANE;
        conv5x5_8(xp, h, w0a, sw0, b0v, sa);
        conv5x5_8(xp, h, w0b, sw0, b0v, sbx);
    }
    mfma_plane(ipT0, BHm, aV, aH2, spc + (size_t)(q4 + 8) * PLANE, wid, l15, l16, bv1);
    pack_plane(sa, sbx, ipT1, h, w0a, w0b, aH3);
    __syncthreads();

    // ---- final: MFMA(pl3) ----
    mfma_plane(ipT1, BHm, aV, aH3, spc + (size_t)(q4 + 12) * PLANE, wid, l15, l16, bv1);
}

// ---------------- wa fp32 -> bf16 ----------------
__global__ __launch_bounds__(256)
void wa_cvt(const float* __restrict__ wa, unsigned short* __restrict__ waB)
{
    const int i = blockIdx.x * 256 + threadIdx.x;   // 36864 float4s
    const float4 v = reinterpret_cast<const float4*>(wa)[i];
    ushort4 o;
    o.x = f2bf(v.x); o.y = f2bf(v.y); o.z = f2bf(v.z); o.w = f2bf(v.w);
    reinterpret_cast<ushort4*>(waB)[i] = o;
}

// ---------------- 1x1 conv as bf16 MFMA GEMM (unchanged) ----------------
__global__ __launch_bounds__(256)
void pw_mfma(const unsigned short* __restrict__ spB,
             const unsigned short* __restrict__ waB,
             const float* __restrict__ ba, float* __restrict__ out)
{
    __shared__ unsigned short As[128 * 64];
    __shared__ unsigned short Bs[128 * 64];

    const int tid  = threadIdx.x;
    const int lane = tid & 63;
    const int wid  = tid >> 6;
    const int wrow = wid >> 1;
    const int wcol = wid & 1;

    const int co0  = blockIdx.y * 128;
    const int col0 = blockIdx.x * 128;

    f32x4 acc[4][4];
    #pragma unroll
    for (int m = 0; m < 4; ++m)
        #pragma unroll
        for (int nn = 0; nn < 4; ++nn) acc[m][nn] = (f32x4){0.f, 0.f, 0.f, 0.f};

    const char* waBb = (const char*)waB;

    for (int kt = 0; kt < 6; ++kt) {
        #pragma unroll
        for (int q = 0; q < 4; ++q) {
            const int L     = (wid * 4 + q) * 1024 + lane * 16;
            const int row   = L >> 7;
            const int kbyte = (L & 127) ^ ((row & 7) << 4);
            const void* src = (const void*)(waBb + (size_t)(co0 + row) * 768 + kt * 128 + kbyte);
            __builtin_amdgcn_global_load_lds(
                (const __attribute__((address_space(1))) void*)src,
                (__attribute__((address_space(3))) void*)((char*)As + (wid * 4 + q) * 1024),
                16, 0, 0);
        }

        #pragma unroll
        for (int j = 0; j < 2; ++j) {
            const int kloc  = j * 32 + 2 * (tid >> 4);
            const int cbase = 8 * (tid & 15);
            const unsigned int* gp =
                (const unsigned int*)(spB + (size_t)(kt * 64 + kloc) * NTOT + col0 + cbase);
            unsigned int g0[4], g1[4];
            *(uint4*)g0 = *(const uint4*)gp;
            *(uint4*)g1 = *(const uint4*)(gp + NTOT / 2);
            #pragma unroll
            for (int r = 0; r < 8; ++r) {
                const unsigned int w0v = g0[r >> 1], w1v = g1[r >> 1];
                const unsigned int lo = (r & 1) ? (w0v >> 16) : (w0v & 0xffffu);
                const unsigned int hi = (r & 1) ? (w1v >> 16) : (w1v & 0xffffu);
                const unsigned int val = lo | (hi << 16);
                const int colL = cbase + r;
                const int s    = (r ^ (tid & 7)) & 7;
                const int byte = colL * 128 + ((kloc * 2) ^ (s << 4));
                *(unsigned int*)((char*)Bs + byte) = val;
            }
        }
        __syncthreads();

        #pragma unroll
        for (int kk = 0; kk < 2; ++kk) {
            short8v aF[4], bF[4];
            const int kbyte = kk * 64 + (lane >> 4) * 16;
            #pragma unroll
            for (int m = 0; m < 4; ++m) {
                const int row = wrow * 64 + m * 16 + (lane & 15);
                aF[m] = *(const short8v*)((const char*)As + row * 128 + (kbyte ^ ((row & 7) << 4)));
            }
            #pragma unroll
            for (int nn = 0; nn < 4; ++nn) {
                const int col = wcol * 64 + nn * 16 + (lane & 15);
                const int s   = ((col & 7) ^ ((col >> 3) & 7)) << 4;
                bF[nn] = *(const short8v*)((const char*)Bs + col * 128 + (kbyte ^ s));
            }
            #pragma unroll
            for (int m = 0; m < 4; ++m)
                #pragma unroll
                for (int nn = 0; nn < 4; ++nn)
                    acc[m][nn] = __builtin_amdgcn_mfma_f32_16x16x32_bf16(
                        aF[m], bF[nn], acc[m][nn], 0, 0, 0);
        }
        __syncthreads();
    }

    const int nb  = col0 >> 12;
    const int px0 = col0 & 4095;
    #pragma unroll
    for (int m = 0; m < 4; ++m) {
        #pragma unroll
        for (int r = 0; r < 4; ++r) {
            const int co = co0 + wrow * 64 + m * 16 + 4 * (lane >> 4) + r;
            const float bv = ba[co];
            float* orow = out + ((size_t)(nb * CCH + co)) * PLANE + px0 + wcol * 64 + (lane & 15);
            #pragma unroll
            for (int nn = 0; nn < 4; ++nn)
                orow[nn * 16] = acc[m][nn][r] + bv;
        }
    }
}

extern "C" void kernel_launch(void* const* d_in, const int* in_sizes, int n_in,
                              void* d_out, int out_size, void* d_ws, size_t ws_size,
                              hipStream_t stream)
{
    const float* x  = (const float*)d_in[0];
    const float* w0 = (const float*)d_in[1];
    const float* b0 = (const float*)d_in[2];
    const float* w1 = (const float*)d_in[3];
    const float* b1 = (const float*)d_in[4];
    const float* w2 = (const float*)d_in[5];
    const float* b2 = (const float*)d_in[6];
    const float* w3 = (const float*)d_in[7];
    const float* b3 = (const float*)d_in[8];
    const float* w4 = (const float*)d_in[9];
    const float* b4 = (const float*)d_in[10];
    const float* w5 = (const float*)d_in[11];
    const float* b5 = (const float*)d_in[12];
    const float* w6 = (const float*)d_in[13];
    const float* b6 = (const float*)d_in[14];
    const float* wa = (const float*)d_in[15];
    const float* ba = (const float*)d_in[16];
    float* out = (float*)d_out;

    unsigned short* spB = (unsigned short*)d_ws;                       // 50,331,648 B
    unsigned short* waB = (unsigned short*)((char*)d_ws + 50331648);   // 294,912 B

    wa_cvt<<<dim3(36864 / 256), 256, 0, stream>>>(wa, waB);
    dw_fused<<<dim3(CCH * 4), 256, 0, stream>>>(
        x, w0, b0, w1, b1, w2, b2, w3, b3, w4, b4, w5, b5, w6, b6, spB);
    pw_mfma<<<dim3(NTOT / 128, CCH / 128), 256, 0, stream>>>(spB, waB, ba, out);
}